// Round 7
// baseline (1015.647 us; speedup 1.0000x reference)
//
#include <hip/hip_runtime.h>
#include <stdint.h>
#include <stddef.h>

typedef _Float16 f16;
typedef _Float16 f16x8 __attribute__((ext_vector_type(8)));
typedef _Float16 f16x4 __attribute__((ext_vector_type(4)));
typedef float f32x4 __attribute__((ext_vector_type(4)));

#define NB 8192
#define DK 256

// ---------- DPP xor-add reduction over 16-lane groups ----------
template<int CTRL>
__device__ __forceinline__ float dpp_add(float x) {
  int yi = __builtin_amdgcn_mov_dpp(__float_as_int(x), CTRL, 0xF, 0xF, true);
  return x + __int_as_float(yi);
}
__device__ __forceinline__ float reduce16(float x) {
  x = dpp_add<0xB1>(x);   // pairs
  x = dpp_add<0x4E>(x);   // quads
  x = dpp_add<0x141>(x);  // cross-quad (8)
  x = dpp_add<0x140>(x);  // cross-octet (16)
  return x;
}

// ---------- prep: L2-normalize rows, fold in 1/sqrt(temperature), convert to fp16 ----------
__global__ __launch_bounds__(256) void prep_kernel(const float* __restrict__ f_img,
                                                   const float* __restrict__ f_txt,
                                                   f16* __restrict__ fi16,
                                                   f16* __restrict__ ft16) {
  const int wave = threadIdx.x >> 6, lane = threadIdx.x & 63;
  const int row = blockIdx.x * 4 + wave;
  const float* src = (row < NB) ? f_img : f_txt;
  f16* dst = (row < NB) ? fi16 : ft16;
  const int r = row & (NB - 1);
  const float4 v = *reinterpret_cast<const float4*>(src + (size_t)r * DK + lane * 4);
  float ss = v.x * v.x + v.y * v.y + v.z * v.z + v.w * v.w;
  #pragma unroll
  for (int d = 1; d < 64; d <<= 1) ss += __shfl_xor(ss, d, 64);
  const float sc = 3.7796447300922722f / sqrtf(ss);   // (1/||x||)/sqrt(0.07)
  f16x4 o;
  o[0] = (f16)(v.x * sc); o[1] = (f16)(v.y * sc);
  o[2] = (f16)(v.z * sc); o[3] = (f16)(v.w * sc);
  *reinterpret_cast<f16x4*>(dst + (size_t)r * DK + lane * 4) = o;
}

// ---------- shared tile geometry ----------
// Tile (rt,ct): T1[i][j] = fi[row0+i]·ft[col0+j] (i2t), T2'[i][j] = ft[row0+i]·fi[col0+j] (t2i^T).
// 4 waves, 2x2 over 128x128 (64x64 each). C/D: col=lane&15, row=(lane>>4)*4+reg.

// ================= PASS 1: counts + sum_neg exp + pos bitmask =================
__global__ __launch_bounds__(256, 2) void hloss_pass1(
    const f16* __restrict__ fi16, const f16* __restrict__ ft16,
    const float* __restrict__ scores,
    float* __restrict__ s_row, float* __restrict__ s_col,
    float* __restrict__ cnt_neg, float* __restrict__ cnt_pos,
    uint8_t* __restrict__ posmask)
{
  __shared__ __align__(16) char smem[65536];
  const int bid = blockIdx.x;
  const int swz = (bid & 7) * 512 + (bid >> 3);
  const int rt = swz >> 6, ct = swz & 63;
  const int row0 = rt << 7, col0 = ct << 7;
  const int tid = threadIdx.x;
  const int wave = tid >> 6, lane = tid & 63;
  const int wr = wave >> 1, wc = wave & 1;

  f32x4 acc1[4][4], acc2[4][4];
  #pragma unroll
  for (int m = 0; m < 4; ++m)
    #pragma unroll
    for (int n = 0; n < 4; ++n) { acc1[m][n] = {0,0,0,0}; acc2[m][n] = {0,0,0,0}; }

  const f16* psrc = (wave == 0) ? (fi16 + (size_t)row0 * DK)
                  : (wave == 1) ? (ft16 + (size_t)col0 * DK)
                  : (wave == 2) ? (ft16 + (size_t)row0 * DK)
                                : (fi16 + (size_t)col0 * DK);
  char* const pbase = smem + (wave << 14);
  const int sub = lane >> 3;
  const int sslot = ((lane & 7) ^ sub) << 4;

  const int fr = lane & 15;
  const int fg = lane >> 4;
  const int rswz = (fr & 7) << 4;

  const int rbase = row0 + (wr << 6) + (fg << 2);
  const int cbase = col0 + (wc << 6) + fr;

  float sc[4][4][4];   // [m][n][reg] — all indices compile-time (rule #20)

  for (int kt = 0; kt < 4; ++kt) {
    __syncthreads();
    #pragma unroll
    for (int i = 0; i < 16; ++i) {
      const char* g = (const char*)psrc + (((i << 3) + sub) << 9) + (kt << 7) + sslot;
      __builtin_amdgcn_global_load_lds(
          (const __attribute__((address_space(1))) uint32_t*)g,
          (__attribute__((address_space(3))) uint32_t*)(pbase + (i << 10)),
          16, 0, 0);
    }
    // scores slab m=kt rides the staging pipeline (drained by the same pre-barrier vmcnt)
    #pragma unroll
    for (int n = 0; n < 4; ++n)
      #pragma unroll
      for (int reg = 0; reg < 4; ++reg)
        sc[kt][n][reg] = __builtin_nontemporal_load(
            &scores[(size_t)(rbase + (kt << 4) + reg) * NB + cbase + (n << 4)]);
    __syncthreads();
    #pragma unroll
    for (int ks = 0; ks < 2; ++ks) {
      const int koff = ((ks << 6) + (fg << 4)) ^ rswz;
      {
        f16x8 a[4], b[4];
        #pragma unroll
        for (int m = 0; m < 4; ++m) {
          a[m] = *reinterpret_cast<const f16x8*>(smem + (((wr << 6) + (m << 4) + fr) << 7) + koff);
          b[m] = *reinterpret_cast<const f16x8*>(smem + 16384 + (((wc << 6) + (m << 4) + fr) << 7) + koff);
        }
        #pragma unroll
        for (int m = 0; m < 4; ++m)
          #pragma unroll
          for (int n = 0; n < 4; ++n)
            acc1[m][n] = __builtin_amdgcn_mfma_f32_16x16x32_f16(a[m], b[n], acc1[m][n], 0, 0, 0);
      }
      {
        f16x8 a[4], b[4];
        #pragma unroll
        for (int m = 0; m < 4; ++m) {
          a[m] = *reinterpret_cast<const f16x8*>(smem + 32768 + (((wr << 6) + (m << 4) + fr) << 7) + koff);
          b[m] = *reinterpret_cast<const f16x8*>(smem + 49152 + (((wc << 6) + (m << 4) + fr) << 7) + koff);
        }
        #pragma unroll
        for (int m = 0; m < 4; ++m)
          #pragma unroll
          for (int n = 0; n < 4; ++n)
            acc2[m][n] = __builtin_amdgcn_mfma_f32_16x16x32_f16(a[m], b[n], acc2[m][n], 0, 0, 0);
      }
    }
  }

  // ---------- epilogue: all scores already in registers ----------
  #pragma unroll
  for (int m = 0; m < 4; ++m) {
    #pragma unroll
    for (int reg = 0; reg < 4; ++reg) {
      const int rg = rbase + (m << 4) + reg;
      float v1 = 0.f, v2 = 0.f, cnp = 0.f;
      uint64_t w = 0;
      #pragma unroll
      for (int n = 0; n < 4; ++n) {
        const float scv = sc[m][n][reg];
        const bool nb = (scv <= 0.3f);
        v1 += nb ? __expf(acc1[m][n][reg]) : 0.f;
        v2 += nb ? __expf(acc2[m][n][reg]) : 0.f;
        cnp += (nb ? 1.f : 0.f) + ((scv > 0.5f) ? 256.f : 0.f);
        const uint64_t bal = __ballot(scv > 0.5f);            // bit i = lane i
        w |= ((bal >> (fg << 4)) & 0xFFFFull) << (n << 4);    // this group's row, cols n*16..+15
      }
      v1 = reduce16(v1); v2 = reduce16(v2); cnp = reduce16(cnp);
      if (fr == 0) {
        atomicAdd(&s_row[rg], v1);
        atomicAdd(&s_col[rg], v2);
        const float cp = floorf(cnp * (1.f / 256.f));
        atomicAdd(&cnt_neg[rg], cnp - 256.f * cp);
        atomicAdd(&cnt_pos[rg], cp);
        // pos bitmask row rg, 4 words (cols col0+wc*64 .. +63), 8B-aligned
        *reinterpret_cast<uint64_t*>(posmask + (size_t)rg * (NB / 8) + (col0 >> 3) + (wc << 3)) = w;
      }
    }
  }
}

// ================= PASS 2: sum_pos softplus(nl - L), no scores =================
__global__ __launch_bounds__(256, 2) void hloss_pass2(
    const f16* __restrict__ fi16, const f16* __restrict__ ft16,
    const uint8_t* __restrict__ posmask,
    const float* __restrict__ nl_row, const float* __restrict__ nl_col,
    float* __restrict__ acc_i2t, float* __restrict__ acc_t2i)
{
  __shared__ __align__(16) char smem[65536];
  const int bid = blockIdx.x;
  const int swz = (bid & 7) * 512 + (bid >> 3);
  const int rt = swz >> 6, ct = swz & 63;
  const int row0 = rt << 7, col0 = ct << 7;
  const int tid = threadIdx.x;
  const int wave = tid >> 6, lane = tid & 63;
  const int wr = wave >> 1, wc = wave & 1;

  f32x4 acc1[4][4], acc2[4][4];
  #pragma unroll
  for (int m = 0; m < 4; ++m)
    #pragma unroll
    for (int n = 0; n < 4; ++n) { acc1[m][n] = {0,0,0,0}; acc2[m][n] = {0,0,0,0}; }

  const f16* psrc = (wave == 0) ? (fi16 + (size_t)row0 * DK)
                  : (wave == 1) ? (ft16 + (size_t)col0 * DK)
                  : (wave == 2) ? (ft16 + (size_t)row0 * DK)
                                : (fi16 + (size_t)col0 * DK);
  char* const pbase = smem + (wave << 14);
  const int sub = lane >> 3;
  const int sslot = ((lane & 7) ^ sub) << 4;

  const int fr = lane & 15;
  const int fg = lane >> 4;
  const int rswz = (fr & 7) << 4;

  const int rbase = row0 + (wr << 6) + (fg << 2);

  // prefetch mask words + nl values (issued before first barrier; drained with staging)
  uint64_t mk[4][4];
  float nlr[4][4], nlc[4][4];
  #pragma unroll
  for (int m = 0; m < 4; ++m)
    #pragma unroll
    for (int reg = 0; reg < 4; ++reg) {
      const int rg = rbase + (m << 4) + reg;
      mk[m][reg] = *reinterpret_cast<const uint64_t*>(
          posmask + (size_t)rg * (NB / 8) + (col0 >> 3) + (wc << 3));
      nlr[m][reg] = nl_row[rg];
      nlc[m][reg] = nl_col[rg];
    }

  for (int kt = 0; kt < 4; ++kt) {
    __syncthreads();
    #pragma unroll
    for (int i = 0; i < 16; ++i) {
      const char* g = (const char*)psrc + (((i << 3) + sub) << 9) + (kt << 7) + sslot;
      __builtin_amdgcn_global_load_lds(
          (const __attribute__((address_space(1))) uint32_t*)g,
          (__attribute__((address_space(3))) uint32_t*)(pbase + (i << 10)),
          16, 0, 0);
    }
    __syncthreads();
    #pragma unroll
    for (int ks = 0; ks < 2; ++ks) {
      const int koff = ((ks << 6) + (fg << 4)) ^ rswz;
      {
        f16x8 a[4], b[4];
        #pragma unroll
        for (int m = 0; m < 4; ++m) {
          a[m] = *reinterpret_cast<const f16x8*>(smem + (((wr << 6) + (m << 4) + fr) << 7) + koff);
          b[m] = *reinterpret_cast<const f16x8*>(smem + 16384 + (((wc << 6) + (m << 4) + fr) << 7) + koff);
        }
        #pragma unroll
        for (int m = 0; m < 4; ++m)
          #pragma unroll
          for (int n = 0; n < 4; ++n)
            acc1[m][n] = __builtin_amdgcn_mfma_f32_16x16x32_f16(a[m], b[n], acc1[m][n], 0, 0, 0);
      }
      {
        f16x8 a[4], b[4];
        #pragma unroll
        for (int m = 0; m < 4; ++m) {
          a[m] = *reinterpret_cast<const f16x8*>(smem + 32768 + (((wr << 6) + (m << 4) + fr) << 7) + koff);
          b[m] = *reinterpret_cast<const f16x8*>(smem + 49152 + (((wc << 6) + (m << 4) + fr) << 7) + koff);
        }
        #pragma unroll
        for (int m = 0; m < 4; ++m)
          #pragma unroll
          for (int n = 0; n < 4; ++n)
            acc2[m][n] = __builtin_amdgcn_mfma_f32_16x16x32_f16(a[m], b[n], acc2[m][n], 0, 0, 0);
      }
    }
  }

  #pragma unroll
  for (int m = 0; m < 4; ++m) {
    #pragma unroll
    for (int reg = 0; reg < 4; ++reg) {
      const int rg = rbase + (m << 4) + reg;
      const float vnlr = nlr[m][reg], vnlc = nlc[m][reg];
      const uint64_t w = mk[m][reg];
      float v1 = 0.f, v2 = 0.f;
      #pragma unroll
      for (int n = 0; n < 4; ++n) {
        const bool pb = (w >> ((n << 4) + fr)) & 1ull;
        const float z1 = vnlr - acc1[m][n][reg];
        const float z2 = vnlc - acc2[m][n][reg];
        // softplus(z) = max(z,0) + log1p(exp(-|z|)); exact at z = -inf
        const float t1 = fmaxf(z1, 0.f) + __logf(1.f + __expf(-fabsf(z1)));
        const float t2 = fmaxf(z2, 0.f) + __logf(1.f + __expf(-fabsf(z2)));
        v1 += pb ? t1 : 0.f;
        v2 += pb ? t2 : 0.f;
      }
      v1 = reduce16(v1); v2 = reduce16(v2);
      if (fr == 0) {
        atomicAdd(&acc_i2t[rg], v1);
        atomicAdd(&acc_t2i[rg], v2);
      }
    }
  }
}

// ---------- nl = log(sum_exp) ----------
__global__ __launch_bounds__(256) void mid_kernel(const float* __restrict__ s_row,
                                                  const float* __restrict__ s_col,
                                                  float* __restrict__ nl_row,
                                                  float* __restrict__ nl_col) {
  const int i = blockIdx.x * 256 + threadIdx.x;
  nl_row[i] = logf(s_row[i]);
  nl_col[i] = logf(s_col[i]);
}

// ---------- final scalar reduction (32 blocks + atomic) ----------
__global__ __launch_bounds__(256) void final_kernel(const float* __restrict__ acc_i2t,
                                                    const float* __restrict__ acc_t2i,
                                                    const float* __restrict__ cnt_neg,
                                                    const float* __restrict__ cnt_pos,
                                                    float* __restrict__ out) {
  const int i = blockIdx.x * 256 + threadIdx.x;
  const float denom = (1.0f + cnt_neg[i]) * cnt_pos[i];
  float t = 0.5f * (acc_i2t[i] + acc_t2i[i]) / denom;
  #pragma unroll
  for (int d = 1; d < 64; d <<= 1) t += __shfl_xor(t, d, 64);
  __shared__ float wsum[4];
  if ((threadIdx.x & 63) == 0) wsum[threadIdx.x >> 6] = t;
  __syncthreads();
  if (threadIdx.x == 0)
    atomicAdd(out, (wsum[0] + wsum[1] + wsum[2] + wsum[3]) * (1.0f / (float)NB));
}

extern "C" void kernel_launch(void* const* d_in, const int* in_sizes, int n_in,
                              void* d_out, int out_size, void* d_ws, size_t ws_size,
                              hipStream_t stream) {
  (void)in_sizes; (void)n_in; (void)out_size; (void)ws_size;
  const float* f_img  = (const float*)d_in[0];
  const float* f_txt  = (const float*)d_in[1];
  const float* scores = (const float*)d_in[2];

  char* ws = (char*)d_ws;
  f16* fi16 = (f16*)ws;                                   // 4 MiB
  f16* ft16 = (f16*)(ws + (size_t)(4 << 20));             // 4 MiB
  float* s_row   = (float*)(ws + (size_t)(8 << 20));      // 8 arrays x 32 KiB
  float* s_col   = s_row + NB;
  float* cnt_neg = s_row + 2 * NB;
  float* cnt_pos = s_row + 3 * NB;
  float* acc_i2t = s_row + 4 * NB;
  float* acc_t2i = s_row + 5 * NB;
  float* nl_row  = s_row + 6 * NB;
  float* nl_col  = s_row + 7 * NB;
  uint8_t* posmask = (uint8_t*)(ws + (size_t)(16 << 20)); // 8 MiB (8192 x 1024 B)

  (void)hipMemsetAsync(s_row, 0, 6 * NB * sizeof(float), stream);
  (void)hipMemsetAsync(d_out, 0, sizeof(float), stream);
  hipLaunchKernelGGL(prep_kernel, dim3(4096), dim3(256), 0, stream, f_img, f_txt, fi16, ft16);
  hipLaunchKernelGGL(hloss_pass1, dim3(4096), dim3(256), 0, stream,
                     fi16, ft16, scores, s_row, s_col, cnt_neg, cnt_pos, posmask);
  hipLaunchKernelGGL(mid_kernel, dim3(32), dim3(256), 0, stream, s_row, s_col, nl_row, nl_col);
  hipLaunchKernelGGL(hloss_pass2, dim3(4096), dim3(256), 0, stream,
                     fi16, ft16, posmask, nl_row, nl_col, acc_i2t, acc_t2i);
  hipLaunchKernelGGL(final_kernel, dim3(32), dim3(256), 0, stream,
                     acc_i2t, acc_t2i, cnt_neg, cnt_pos, (float*)d_out);
}